// Round 7
// baseline (229.614 us; speedup 1.0000x reference)
//
#include <hip/hip_runtime.h>
#include <hip/hip_bf16.h>

// RGCN layer: out = relu( segment_sum(blockdiag_msg) * norm + h @ loop_weight )
//
// Inputs (setup_inputs order):
//   0: h           [N,128]  f32
//   1: norm        [N,1]    f32
//   2: weight      [R,1024] f32   (R x NB(16) x SI(8) x SO(8))
//   3: loop_weight [128,128] f32
//   4: src         [E] i32
//   5: dst         [E] i32
//   6: etype       [E] i32
// Output: [N,128] f32
//
// Round-6: rounds 4/5 proved agg is NOT chain-latency-bound (two
// parallelism restructures = neutral); model says L1-miss-path (MSHR)
// bound on the per-edge 2KB weight gather. Revert agg to the proven
// round-3 single-wave form; add nontemporal loads on the zero-reuse
// gather streams (w16/h16/srcet) to bypass L1 fill; vectorize hist and
// scatter 4 edges/thread. Sort + dot2 + MFMA gemm retained.

#define IN_FEAT 128
#define OUT_FEAT 128
#define SCAN_CHUNK 512

using short8  = __attribute__((ext_vector_type(8))) short;
using float4v = __attribute__((ext_vector_type(4))) float;
using uintx4  = __attribute__((ext_vector_type(4))) unsigned;
using intx2   = __attribute__((ext_vector_type(2))) int;

__device__ inline float blo(unsigned u) { return __uint_as_float(u << 16); }
__device__ inline float bhi(unsigned u) { return __uint_as_float(u & 0xffff0000u); }
__device__ inline unsigned short f2bf(float f) {
  __hip_bfloat16 b = __float2bfloat16(f);
  return *reinterpret_cast<unsigned short*>(&b);
}

// dword = 2 packed bf16; returns c + x.lo*w.lo + x.hi*w.hi
__device__ inline float dot2bf(unsigned x, unsigned w, float c) {
#if __has_builtin(__builtin_amdgcn_fdot2_f32_bf16)
  typedef __bf16 bf16x2 __attribute__((ext_vector_type(2)));
  return __builtin_amdgcn_fdot2_f32_bf16(__builtin_bit_cast(bf16x2, x),
                                         __builtin_bit_cast(bf16x2, w), c, false);
#else
  return c + blo(x) * blo(w) + bhi(x) * bhi(w);
#endif
}

// ---------------------------------------------------------------------------
// Fused prologue: [wpack | hpack | lwpack | hist(x4)] by blockIdx range.
// wpack (dot2 layout): w16[r][b*64 + opp*16 + j*8 + i] = bf16(w[r][b*64 + i*8 + opp*2 + j])
// hpack: h16 row-major bf16 copy of h.
// lwpack: lwT[o*128 + k] = bf16(lw[k*128 + o])  (col-major for MFMA B-frags).
// hist: cnt[dst[e]]++ with int4 loads, 4 edges/thread (cnt pre-zeroed).
// ---------------------------------------------------------------------------
__global__ __launch_bounds__(256) void k_prep(
    const float* __restrict__ w, unsigned short* __restrict__ w16, int wtotal,
    const float* __restrict__ h, uint4* __restrict__ h16p, int htotal8,
    const float* __restrict__ lw, unsigned short* __restrict__ lwT,
    const int* __restrict__ dst, int* __restrict__ cnt, int E,
    int bw, int bh, int blw) {
  const int bid = blockIdx.x;
  if (bid < bw) {
    const int idx = bid * 256 + threadIdx.x;
    if (idx < wtotal) {
      const int r = idx >> 10;
      const int rem = idx & 1023;
      const int b = rem >> 6;
      const int q = rem & 63;
      const int opp = q >> 4;
      const int t = q & 15;
      const int j = t >> 3;
      const int i = t & 7;
      w16[idx] = f2bf(w[((size_t)r << 10) + b * 64 + i * 8 + opp * 2 + j]);
    }
  } else if (bid < bw + bh) {
    const int t = (bid - bw) * 256 + threadIdx.x;
    if (t < htotal8) {
      const float4 a = ((const float4*)h)[2 * t];
      const float4 b = ((const float4*)h)[2 * t + 1];
      uint4 o;
      o.x = (unsigned)f2bf(a.x) | ((unsigned)f2bf(a.y) << 16);
      o.y = (unsigned)f2bf(a.z) | ((unsigned)f2bf(a.w) << 16);
      o.z = (unsigned)f2bf(b.x) | ((unsigned)f2bf(b.y) << 16);
      o.w = (unsigned)f2bf(b.z) | ((unsigned)f2bf(b.w) << 16);
      h16p[t] = o;
    }
  } else if (bid < bw + bh + blw) {
    const int idx = (bid - bw - bh) * 256 + threadIdx.x;
    if (idx < IN_FEAT * OUT_FEAT) {
      const int o = idx >> 7;
      const int k = idx & 127;
      lwT[idx] = f2bf(lw[k * 128 + o]);
    }
  } else {
    const int e0 = ((bid - bw - bh - blw) * 256 + threadIdx.x) * 4;
    if (e0 + 3 < E) {
      const int4 d4 = *(const int4*)(dst + e0);
      atomicAdd(&cnt[d4.x], 1);
      atomicAdd(&cnt[d4.y], 1);
      atomicAdd(&cnt[d4.z], 1);
      atomicAdd(&cnt[d4.w], 1);
    } else {
      for (int e = e0; e < E; ++e) atomicAdd(&cnt[dst[e]], 1);
    }
  }
}

// ---------------------------------------------------------------------------
// Fused: [self-loop MFMA GEMM | chunksum] by blockIdx range.
// GEMM: out = h16 @ lw (bf16 in, f32 out).  chunksum: bsum[c] = sum cnt.
// ---------------------------------------------------------------------------
__global__ __launch_bounds__(256) void k_gemm_sum(
    const unsigned short* __restrict__ h16, const unsigned short* __restrict__ lwT,
    float* __restrict__ out, int N,
    const int* __restrict__ cnt, int* __restrict__ bsum, int gemm_blocks) {
  if (blockIdx.x < gemm_blocks) {
    const int wid = threadIdx.x >> 6;
    const int lane = threadIdx.x & 63;
    const int row0 = blockIdx.x * 64 + wid * 16;
    if (row0 >= N) return;  // whole-wave exit; no barriers in this branch
    const int m = lane & 15;
    const int kg = (lane >> 4) * 8;
    const int arow = min(row0 + m, N - 1);

    float4v acc[8];
    #pragma unroll
    for (int nt = 0; nt < 8; ++nt) acc[nt] = (float4v){0.f, 0.f, 0.f, 0.f};

    const unsigned short* ap = h16 + (size_t)arow * 128 + kg;
    const unsigned short* bp = lwT + (size_t)m * 128 + kg;

    #pragma unroll
    for (int kc = 0; kc < 4; ++kc) {
      const short8 a = *(const short8*)(ap + kc * 32);
      #pragma unroll
      for (int nt = 0; nt < 8; ++nt) {
        const short8 b = *(const short8*)(bp + nt * 2048 + kc * 32);
        acc[nt] = __builtin_amdgcn_mfma_f32_16x16x32_bf16(a, b, acc[nt], 0, 0, 0);
      }
    }

    const int crow = row0 + (lane >> 4) * 4;
    #pragma unroll
    for (int nt = 0; nt < 8; ++nt) {
      #pragma unroll
      for (int r = 0; r < 4; ++r) {
        const int row = crow + r;
        if (row < N) out[(size_t)row * 128 + nt * 16 + m] = acc[nt][r];
      }
    }
  } else {
    __shared__ int s[256];
    const int cb = blockIdx.x - gemm_blocks;
    const int t = threadIdx.x;
    const int base = cb * SCAN_CHUNK;
    int v = 0;
    const int i0 = base + t, i1 = base + 256 + t;
    if (i0 < N) v += cnt[i0];
    if (i1 < N) v += cnt[i1];
    s[t] = v;
    __syncthreads();
    for (int d = 128; d > 0; d >>= 1) {
      if (t < d) s[t] += s[t + d];
      __syncthreads();
    }
    if (t == 0) bsum[cb] = s[0];
  }
}

// standalone chunksum (fallback path)
__global__ __launch_bounds__(256) void k_chunksum(
    const int* __restrict__ cnt, int* __restrict__ bsum, int N) {
  __shared__ int s[256];
  const int t = threadIdx.x;
  const int base = blockIdx.x * SCAN_CHUNK;
  int v = 0;
  int i0 = base + t, i1 = base + 256 + t;
  if (i0 < N) v += cnt[i0];
  if (i1 < N) v += cnt[i1];
  s[t] = v;
  __syncthreads();
  for (int d = 128; d > 0; d >>= 1) {
    if (t < d) s[t] += s[t + d];
    __syncthreads();
  }
  if (t == 0) bsum[blockIdx.x] = s[0];
}

__global__ __launch_bounds__(256) void k_hist(
    const int* __restrict__ dst, int* __restrict__ cnt, int E) {
  const int e = blockIdx.x * blockDim.x + threadIdx.x;
  if (e < E) atomicAdd(&cnt[dst[e]], 1);
}

// ---------------------------------------------------------------------------
// Per-chunk exclusive scan writing pos; each block derives its own chunk
// prefix from bsum with a strided wave-0 reduction.
// ---------------------------------------------------------------------------
__global__ __launch_bounds__(256) void k_offsets(
    const int* __restrict__ cnt, const int* __restrict__ bsum,
    int* __restrict__ pos, int N) {
  __shared__ int s[256];
  __shared__ int sbase;
  const int t = threadIdx.x;
  if (t < 64) {
    int acc = 0;
    for (int j = t; j < (int)blockIdx.x; j += 64) acc += bsum[j];
    #pragma unroll
    for (int d = 1; d < 64; d <<= 1) acc += __shfl_xor(acc, d);
    if (t == 0) sbase = acc;
  }
  const int base = blockIdx.x * SCAN_CHUNK;
  const int i0 = base + 2 * t;
  const int i1 = i0 + 1;
  const int c0 = (i0 < N) ? cnt[i0] : 0;
  const int c1 = (i1 < N) ? cnt[i1] : 0;
  const int pair = c0 + c1;
  s[t] = pair;
  __syncthreads();
  #pragma unroll
  for (int d = 1; d < 256; d <<= 1) {
    int v = (t >= d) ? s[t - d] : 0;
    __syncthreads();
    s[t] += v;
    __syncthreads();
  }
  const int ex = s[t] - pair + sbase;  // exclusive prefix
  if (i0 < N) pos[i0] = ex;
  if (i1 < N) pos[i1] = ex + c0;
}

// 4 edges/thread, int4 loads.
__global__ __launch_bounds__(256) void k_scatter(
    const int* __restrict__ src, const int* __restrict__ dst,
    const int* __restrict__ etype, int* __restrict__ pos,
    int2* __restrict__ srcet, int E) {
  const int e0 = (blockIdx.x * blockDim.x + threadIdx.x) * 4;
  if (e0 + 3 < E) {
    const int4 s4 = *(const int4*)(src + e0);
    const int4 d4 = *(const int4*)(dst + e0);
    const int4 t4 = *(const int4*)(etype + e0);
    int p;
    p = atomicAdd(&pos[d4.x], 1); srcet[p] = make_int2(s4.x, t4.x);
    p = atomicAdd(&pos[d4.y], 1); srcet[p] = make_int2(s4.y, t4.y);
    p = atomicAdd(&pos[d4.z], 1); srcet[p] = make_int2(s4.z, t4.z);
    p = atomicAdd(&pos[d4.w], 1); srcet[p] = make_int2(s4.w, t4.w);
  } else {
    for (int e = e0; e < E; ++e) {
      const int p = atomicAdd(&pos[dst[e]], 1);
      srcet[p] = make_int2(src[e], etype[e]);
    }
  }
}

// ---------------------------------------------------------------------------
// bf16 aggregation (round-3 structure): one wave per node; lane (b,opp)
// owns outputs o = b*8+opp*2, o+1. Per edge: 3 x 16B nontemporal loads
// (no L1 reuse exists on these streams) + 8 dot2. Fused epilogue:
// out = relu(out + acc*norm)   (out holds loop_message).
// ---------------------------------------------------------------------------
__global__ __launch_bounds__(256) void agg_bf16(
    const unsigned short* __restrict__ h16, const float* __restrict__ norm,
    const unsigned short* __restrict__ w16, const int* __restrict__ pos,
    const int* __restrict__ cnt, const int2* __restrict__ srcet,
    float* __restrict__ out, int N) {
  const int node = (int)((blockIdx.x * blockDim.x + threadIdx.x) >> 6);
  const int lane = threadIdx.x & 63;
  if (node >= N) return;

  const int b = lane >> 2;
  const int opp = lane & 3;
  const int woff = b * 64 + opp * 16;  // ushort units
  const int hoff = b * 8;

  const int num = cnt[node];
  const int end = pos[node];
  const int begin = end - num;

  float a0 = 0.f, a1 = 0.f;

  for (int base = 0; base < num; base += 64) {
    const int cn = min(64, num - base);
    const intx2 my = __builtin_nontemporal_load(
        (const intx2*)(srcet + begin + base + min(lane, cn - 1)));
    #pragma unroll 4
    for (int i = 0; i < cn; ++i) {
      const int s = __shfl(my[0], i);
      const int r = __shfl(my[1], i);
      const unsigned short* wp = w16 + ((size_t)r << 10) + woff;
      const uintx4 wa = __builtin_nontemporal_load((const uintx4*)wp);
      const uintx4 wb = __builtin_nontemporal_load((const uintx4*)(wp + 8));
      const uintx4 xv = __builtin_nontemporal_load(
          (const uintx4*)(h16 + ((size_t)s << 7) + hoff));

      a0 = dot2bf(xv[0], wa[0], a0);
      a0 = dot2bf(xv[1], wa[1], a0);
      a0 = dot2bf(xv[2], wa[2], a0);
      a0 = dot2bf(xv[3], wa[3], a0);
      a1 = dot2bf(xv[0], wb[0], a1);
      a1 = dot2bf(xv[1], wb[1], a1);
      a1 = dot2bf(xv[2], wb[2], a1);
      a1 = dot2bf(xv[3], wb[3], a1);
    }
  }

  const float nm = norm[node];
  const int o = b * 8 + opp * 2;
  float* outp = out + ((size_t)node << 7) + o;
  float2 prev = *(const float2*)outp;
  float2 res;
  res.x = fmaxf(prev.x + a0 * nm, 0.f);
  res.y = fmaxf(prev.y + a1 * nm, 0.f);
  *(float2*)outp = res;
}

// ---------------------------------------------------------------------------
// f32 self-loop GEMM (fallback paths only).
// ---------------------------------------------------------------------------
__global__ __launch_bounds__(256) void selfloop_gemm(
    const float* __restrict__ h, const float* __restrict__ lw,
    float* __restrict__ out, int n) {
  __shared__ float slw[IN_FEAT * OUT_FEAT];  // 64 KB
  __shared__ float sh[32 * IN_FEAT];         // 16 KB

  {
    const float4* s4 = (const float4*)lw;
    float4* d4 = (float4*)slw;
    for (int i = threadIdx.x; i < IN_FEAT * OUT_FEAT / 4; i += 256) d4[i] = s4[i];
  }

  const int cg = threadIdx.x & 31;
  const int rg = threadIdx.x >> 5;

  for (int base = blockIdx.x * 32; base < n; base += gridDim.x * 32) {
    const int nrows = min(32, n - base);
    __syncthreads();
    {
      const float4* hs = (const float4*)(h + (size_t)base * IN_FEAT);
      float4* sd = (float4*)sh;
      const int cnt = nrows * (IN_FEAT / 4);
      for (int i = threadIdx.x; i < cnt; i += 256) sd[i] = hs[i];
    }
    __syncthreads();

    float4 acc[4];
    #pragma unroll
    for (int j = 0; j < 4; ++j) acc[j] = make_float4(0.f, 0.f, 0.f, 0.f);

    #pragma unroll 4
    for (int k = 0; k < IN_FEAT; ++k) {
      const float4 w = ((const float4*)slw)[k * 32 + cg];
      #pragma unroll
      for (int j = 0; j < 4; ++j) {
        const float hv = sh[(rg + 8 * j) * IN_FEAT + k];
        acc[j].x += hv * w.x;
        acc[j].y += hv * w.y;
        acc[j].z += hv * w.z;
        acc[j].w += hv * w.w;
      }
    }

    #pragma unroll
    for (int j = 0; j < 4; ++j) {
      const int r = rg + 8 * j;
      if (r < nrows) {
        ((float4*)(out + (size_t)(base + r) * OUT_FEAT))[cg] = acc[j];
      }
    }
  }
}

// ---------------------------------------------------------------------------
// f32 aggregation (middle fallback: ws fits sort but not bf16 buffers)
// ---------------------------------------------------------------------------
__global__ __launch_bounds__(256) void agg(
    const float* __restrict__ h, const float* __restrict__ norm,
    const float* __restrict__ weight, const int* __restrict__ pos,
    const int* __restrict__ cnt, const int2* __restrict__ srcet,
    float* __restrict__ out, int N) {
  const int node = (int)((blockIdx.x * blockDim.x + threadIdx.x) >> 6);
  const int lane = threadIdx.x & 63;
  if (node >= N) return;

  const int b = lane >> 2;
  const int op = (lane & 3) * 2;
  const int boff = b * 64 + op;

  const int num = cnt[node];
  const int end = pos[node];
  const int begin = end - num;

  float a0 = 0.f, a1 = 0.f;

  for (int base = 0; base < num; base += 64) {
    const int cn = min(64, num - base);
    const int2 my = srcet[begin + base + min(lane, cn - 1)];
    #pragma unroll 2
    for (int i = 0; i < cn; ++i) {
      const int s = __shfl(my.x, i);
      const int r = __shfl(my.y, i);
      const float* xp = h + ((size_t)s << 7) + b * 8;
      const float4 x0 = ((const float4*)xp)[0];
      const float4 x1 = ((const float4*)xp)[1];
      const float* wp = weight + ((size_t)r << 10) + boff;
      const float2 w0 = *(const float2*)(wp);
      const float2 w1 = *(const float2*)(wp + 8);
      const float2 w2 = *(const float2*)(wp + 16);
      const float2 w3 = *(const float2*)(wp + 24);
      const float2 w4 = *(const float2*)(wp + 32);
      const float2 w5 = *(const float2*)(wp + 40);
      const float2 w6 = *(const float2*)(wp + 48);
      const float2 w7 = *(const float2*)(wp + 56);
      a0 += x0.x * w0.x; a1 += x0.x * w0.y;
      a0 += x0.y * w1.x; a1 += x0.y * w1.y;
      a0 += x0.z * w2.x; a1 += x0.z * w2.y;
      a0 += x0.w * w3.x; a1 += x0.w * w3.y;
      a0 += x1.x * w4.x; a1 += x1.x * w4.y;
      a0 += x1.y * w5.x; a1 += x1.y * w5.y;
      a0 += x1.z * w6.x; a1 += x1.z * w6.y;
      a0 += x1.w * w7.x; a1 += x1.w * w7.y;
    }
  }

  const float nm = norm[node];
  const int o = b * 8 + op;
  float* outp = out + ((size_t)node << 7) + o;
  float2 prev = *(const float2*)outp;
  float2 res;
  res.x = fmaxf(prev.x + a0 * nm, 0.f);
  res.y = fmaxf(prev.y + a1 * nm, 0.f);
  *(float2*)outp = res;
}

// ---------------------------------------------------------------------------
// Last-resort fallback: per-edge atomics + separate relu.
// ---------------------------------------------------------------------------
__global__ __launch_bounds__(256) void edge_msg(
    const float* __restrict__ h, const float* __restrict__ norm,
    const float* __restrict__ weight, const int* __restrict__ src,
    const int* __restrict__ dst, const int* __restrict__ etype,
    float* out, int E) {
  const int wave = (int)((blockIdx.x * blockDim.x + threadIdx.x) >> 6);
  const int lane = threadIdx.x & 63;
  if (wave >= E) return;

  const int s = src[wave];
  const int d = dst[wave];
  const int r = etype[wave];
  const float nrm = norm[d];

  const int b = lane >> 2;
  const int op = (lane & 3) * 2;

  const float* xp = h + (size_t)s * IN_FEAT + b * 8;
  const float4 x0 = ((const float4*)xp)[0];
  const float4 x1 = ((const float4*)xp)[1];
  float x[8] = {x0.x, x0.y, x0.z, x0.w, x1.x, x1.y, x1.z, x1.w};

  const float* wp = weight + (size_t)r * 1024 + b * 64 + op;
  float a0 = 0.f, a1 = 0.f;
  #pragma unroll
  for (int i = 0; i < 8; ++i) {
    const float2 w = *(const float2*)(wp + i * 8);
    a0 += x[i] * w.x;
    a1 += x[i] * w.y;
  }

  const int o = b * 8 + op;
  float* outp = out + (size_t)d * OUT_FEAT + o;
  atomicAdd(outp, a0 * nrm);
  atomicAdd(outp + 1, a1 * nrm);
}

__global__ __launch_bounds__(256) void relu_k(float* __restrict__ out, int n4) {
  const int i = blockIdx.x * blockDim.x + threadIdx.x;
  if (i < n4) {
    float4 v = ((const float4*)out)[i];
    v.x = fmaxf(v.x, 0.f);
    v.y = fmaxf(v.y, 0.f);
    v.z = fmaxf(v.z, 0.f);
    v.w = fmaxf(v.w, 0.f);
    ((float4*)out)[i] = v;
  }
}

extern "C" void kernel_launch(void* const* d_in, const int* in_sizes, int n_in,
                              void* d_out, int out_size, void* d_ws, size_t ws_size,
                              hipStream_t stream) {
  const float* h    = (const float*)d_in[0];
  const float* norm = (const float*)d_in[1];
  const float* w    = (const float*)d_in[2];
  const float* lw   = (const float*)d_in[3];
  const int* src    = (const int*)d_in[4];
  const int* dst    = (const int*)d_in[5];
  const int* etype  = (const int*)d_in[6];
  float* out = (float*)d_out;

  const int N = in_sizes[1];            // norm has N elements
  const int E = in_sizes[4];            // src has E elements
  const int R = in_sizes[2] / 1024;     // weight rows
  const int nblk = (N + SCAN_CHUNK - 1) / SCAN_CHUNK;

  // ws layout: srcet[E] int2 | cnt[N] | pos[N] | bsum[max(nblk,128)] |
  //            h16[N*128] bf16 | w16[R*1024] bf16 | lwT[128*128] bf16
  const size_t nb_bsum = (size_t)((nblk < 128) ? 128 : nblk);
  const size_t off_cnt  = (size_t)E * 8;
  const size_t off_pos  = off_cnt + (size_t)N * 4;
  const size_t off_bsum = off_pos + (size_t)N * 4;
  size_t off_h16 = off_bsum + nb_bsum * 4;
  off_h16 = (off_h16 + 15) & ~(size_t)15;
  const size_t off_w16 = off_h16 + (size_t)N * IN_FEAT * 2;
  const size_t off_lwT = off_w16 + (size_t)R * 1024 * 2;
  const size_t need_full = off_lwT + (size_t)IN_FEAT * OUT_FEAT * 2;
  const size_t need_sort = off_bsum + nb_bsum * 4;

  if (ws_size >= need_full) {
    char* wsb = (char*)d_ws;
    int2* srcet = (int2*)wsb;
    int* cnt  = (int*)(wsb + off_cnt);
    int* pos  = (int*)(wsb + off_pos);
    int* bsum = (int*)(wsb + off_bsum);
    unsigned short* h16 = (unsigned short*)(wsb + off_h16);
    unsigned short* w16 = (unsigned short*)(wsb + off_w16);
    unsigned short* lwT = (unsigned short*)(wsb + off_lwT);

    hipMemsetAsync(cnt, 0, (size_t)N * 4, stream);

    // fused prologue: wpack + hpack + lwpack + hist (4 edges/thread)
    const int wtotal = R * 1024;
    const int htotal8 = N * IN_FEAT / 8;
    const int bw  = (wtotal + 255) / 256;
    const int bh  = (htotal8 + 255) / 256;
    const int blw = (IN_FEAT * OUT_FEAT + 255) / 256;
    const int bhist = (E + 1023) / 1024;
    k_prep<<<bw + bh + blw + bhist, 256, 0, stream>>>(
        w, w16, wtotal, h, (uint4*)h16, htotal8, lw, lwT, dst, cnt, E,
        bw, bh, blw);

    // fused: self-loop MFMA GEMM (out = loop_message) + chunk sums
    const int gemm_blocks = (N + 63) / 64;
    k_gemm_sum<<<gemm_blocks + nblk, 256, 0, stream>>>(
        h16, lwT, out, N, cnt, bsum, gemm_blocks);

    // offsets (inline bsum prefix) + scatter (4 edges/thread)
    k_offsets<<<nblk, 256, 0, stream>>>(cnt, bsum, pos, N);
    k_scatter<<<(E + 1023) / 1024, 256, 0, stream>>>(src, dst, etype, pos,
                                                     srcet, E);

    // one wave per node; fused norm + self-loop add + relu
    agg_bf16<<<(N + 3) / 4, 256, 0, stream>>>(h16, norm, w16, pos, cnt, srcet,
                                              out, N);
  } else if (ws_size >= need_sort) {
    char* wsb = (char*)d_ws;
    int2* srcet = (int2*)wsb;
    int* cnt  = (int*)(wsb + off_cnt);
    int* pos  = (int*)(wsb + off_pos);
    int* bsum = (int*)(wsb + off_bsum);

    selfloop_gemm<<<512, 256, 0, stream>>>(h, lw, out, N);
    hipMemsetAsync(cnt, 0, (size_t)N * 4, stream);
    k_hist<<<(E + 255) / 256, 256, 0, stream>>>(dst, cnt, E);
    k_chunksum<<<nblk, 256, 0, stream>>>(cnt, bsum, N);
    k_offsets<<<nblk, 256, 0, stream>>>(cnt, bsum, pos, N);
    k_scatter<<<(E + 1023) / 1024, 256, 0, stream>>>(src, dst, etype, pos,
                                                     srcet, E);
    agg<<<(N + 3) / 4, 256, 0, stream>>>(h, norm, w, pos, cnt, srcet, out, N);
  } else {
    selfloop_gemm<<<512, 256, 0, stream>>>(h, lw, out, N);
    edge_msg<<<(E + 3) / 4, 256, 0, stream>>>(h, norm, w, src, dst, etype, out, E);
    const int n4 = N * OUT_FEAT / 4;
    relu_k<<<(n4 + 255) / 256, 256, 0, stream>>>(out, n4);
  }
}

// Round 8
// 148.387 us; speedup vs baseline: 1.5474x; 1.5474x over previous
//
#include <hip/hip_runtime.h>
#include <hip/hip_bf16.h>

// RGCN layer: out = relu( segment_sum(blockdiag_msg) * norm + h @ loop_weight )
//
// Inputs (setup_inputs order):
//   0: h           [N,128]  f32
//   1: norm        [N,1]    f32
//   2: weight      [R,1024] f32   (R x NB(16) x SI(8) x SO(8))
//   3: loop_weight [128,128] f32
//   4: src         [E] i32
//   5: dst         [E] i32
//   6: etype       [E] i32
// Output: [N,128] f32
//
// Round-7: nt loads reverted (r6 showed nt bypasses L2 on gfx950 ->
// weight gather fell to HBM, agg 60->139us). agg back to round-3 proven
// form + two TA-side tweaks: (a) one 16B load serves 4 edges' h rows
// (lane=(edge,chunk) layout, distribute via shfl) -> vmem instrs/edge
// 3 -> 2.25; (b) epilogue prev/norm prefetched before the edge loop.
// k_prep wpack now coalesced: one block per relation, LDS-staged.
// Counting sort + dot2 + MFMA self-loop GEMM + fused dispatches kept.

#define IN_FEAT 128
#define OUT_FEAT 128
#define SCAN_CHUNK 512

using short8  = __attribute__((ext_vector_type(8))) short;
using float4v = __attribute__((ext_vector_type(4))) float;

__device__ inline float blo(unsigned u) { return __uint_as_float(u << 16); }
__device__ inline float bhi(unsigned u) { return __uint_as_float(u & 0xffff0000u); }
__device__ inline unsigned short f2bf(float f) {
  __hip_bfloat16 b = __float2bfloat16(f);
  return *reinterpret_cast<unsigned short*>(&b);
}

// dword = 2 packed bf16; returns c + x.lo*w.lo + x.hi*w.hi
__device__ inline float dot2bf(unsigned x, unsigned w, float c) {
#if __has_builtin(__builtin_amdgcn_fdot2_f32_bf16)
  typedef __bf16 bf16x2 __attribute__((ext_vector_type(2)));
  return __builtin_amdgcn_fdot2_f32_bf16(__builtin_bit_cast(bf16x2, x),
                                         __builtin_bit_cast(bf16x2, w), c, false);
#else
  return c + blo(x) * blo(w) + bhi(x) * bhi(w);
#endif
}

// ---------------------------------------------------------------------------
// Fused prologue: [wpack | hpack | lwpack | hist(x4)] by blockIdx range.
// wpack: one block per relation r. Stage w row (4KB f32) in LDS coalesced,
//   write w16[r][b*64+opp*16+j*8+i] = bf16(w[r][b*64+i*8+opp*2+j]) coalesced.
// hpack: h16 row-major bf16 copy of h (uint4 in/out).
// lwpack: lwT[o*128 + k] = bf16(lw[k*128 + o])  (col-major for MFMA B-frags).
// hist: cnt[dst[e]]++ with int4 loads, 4 edges/thread (cnt pre-zeroed).
// ---------------------------------------------------------------------------
__global__ __launch_bounds__(256) void k_prep(
    const float* __restrict__ w, unsigned short* __restrict__ w16,
    const float* __restrict__ h, uint4* __restrict__ h16p, int htotal8,
    const float* __restrict__ lw, unsigned short* __restrict__ lwT,
    const int* __restrict__ dst, int* __restrict__ cnt, int E,
    int bw, int bh, int blw) {
  __shared__ float srow[1024];
  const int bid = blockIdx.x;
  if (bid < bw) {  // bw == R; one relation per block
    const float* wr = w + ((size_t)bid << 10);
    ((float4*)srow)[threadIdx.x] = ((const float4*)wr)[threadIdx.x];
    __syncthreads();
    const int d0 = threadIdx.x * 4;
    unsigned short o4[4];
    #pragma unroll
    for (int k = 0; k < 4; ++k) {
      const int d = d0 + k;
      const int b = d >> 6;
      const int q = d & 63;
      const int opp = q >> 4;
      const int tt = q & 15;
      const int jj = tt >> 3;
      const int ii = tt & 7;
      o4[k] = f2bf(srow[b * 64 + ii * 8 + opp * 2 + jj]);
    }
    *(uint2*)(w16 + ((size_t)bid << 10) + d0) =
        make_uint2((unsigned)o4[0] | ((unsigned)o4[1] << 16),
                   (unsigned)o4[2] | ((unsigned)o4[3] << 16));
  } else if (bid < bw + bh) {
    const int t = (bid - bw) * 256 + threadIdx.x;
    if (t < htotal8) {
      const float4 a = ((const float4*)h)[2 * t];
      const float4 b = ((const float4*)h)[2 * t + 1];
      uint4 o;
      o.x = (unsigned)f2bf(a.x) | ((unsigned)f2bf(a.y) << 16);
      o.y = (unsigned)f2bf(a.z) | ((unsigned)f2bf(a.w) << 16);
      o.z = (unsigned)f2bf(b.x) | ((unsigned)f2bf(b.y) << 16);
      o.w = (unsigned)f2bf(b.z) | ((unsigned)f2bf(b.w) << 16);
      h16p[t] = o;
    }
  } else if (bid < bw + bh + blw) {
    const int idx = (bid - bw - bh) * 256 + threadIdx.x;
    if (idx < IN_FEAT * OUT_FEAT) {
      const int o = idx >> 7;
      const int k = idx & 127;
      lwT[idx] = f2bf(lw[k * 128 + o]);
    }
  } else {
    const int e0 = ((bid - bw - bh - blw) * 256 + threadIdx.x) * 4;
    if (e0 + 3 < E) {
      const int4 d4 = *(const int4*)(dst + e0);
      atomicAdd(&cnt[d4.x], 1);
      atomicAdd(&cnt[d4.y], 1);
      atomicAdd(&cnt[d4.z], 1);
      atomicAdd(&cnt[d4.w], 1);
    } else {
      for (int e = e0; e < E; ++e) atomicAdd(&cnt[dst[e]], 1);
    }
  }
}

// ---------------------------------------------------------------------------
// Fused: [self-loop MFMA GEMM | chunksum] by blockIdx range.
// GEMM: out = h16 @ lw (bf16 in, f32 out).  chunksum: bsum[c] = sum cnt.
// ---------------------------------------------------------------------------
__global__ __launch_bounds__(256) void k_gemm_sum(
    const unsigned short* __restrict__ h16, const unsigned short* __restrict__ lwT,
    float* __restrict__ out, int N,
    const int* __restrict__ cnt, int* __restrict__ bsum, int gemm_blocks) {
  if (blockIdx.x < gemm_blocks) {
    const int wid = threadIdx.x >> 6;
    const int lane = threadIdx.x & 63;
    const int row0 = blockIdx.x * 64 + wid * 16;
    if (row0 >= N) return;  // whole-wave exit; no barriers in this branch
    const int m = lane & 15;
    const int kg = (lane >> 4) * 8;
    const int arow = min(row0 + m, N - 1);

    float4v acc[8];
    #pragma unroll
    for (int nt = 0; nt < 8; ++nt) acc[nt] = (float4v){0.f, 0.f, 0.f, 0.f};

    const unsigned short* ap = h16 + (size_t)arow * 128 + kg;
    const unsigned short* bp = lwT + (size_t)m * 128 + kg;

    #pragma unroll
    for (int kc = 0; kc < 4; ++kc) {
      const short8 a = *(const short8*)(ap + kc * 32);
      #pragma unroll
      for (int nt = 0; nt < 8; ++nt) {
        const short8 b = *(const short8*)(bp + nt * 2048 + kc * 32);
        acc[nt] = __builtin_amdgcn_mfma_f32_16x16x32_bf16(a, b, acc[nt], 0, 0, 0);
      }
    }

    const int crow = row0 + (lane >> 4) * 4;
    #pragma unroll
    for (int nt = 0; nt < 8; ++nt) {
      #pragma unroll
      for (int r = 0; r < 4; ++r) {
        const int row = crow + r;
        if (row < N) out[(size_t)row * 128 + nt * 16 + m] = acc[nt][r];
      }
    }
  } else {
    __shared__ int s[256];
    const int cb = blockIdx.x - gemm_blocks;
    const int t = threadIdx.x;
    const int base = cb * SCAN_CHUNK;
    int v = 0;
    const int i0 = base + t, i1 = base + 256 + t;
    if (i0 < N) v += cnt[i0];
    if (i1 < N) v += cnt[i1];
    s[t] = v;
    __syncthreads();
    for (int d = 128; d > 0; d >>= 1) {
      if (t < d) s[t] += s[t + d];
      __syncthreads();
    }
    if (t == 0) bsum[cb] = s[0];
  }
}

// standalone chunksum (fallback path)
__global__ __launch_bounds__(256) void k_chunksum(
    const int* __restrict__ cnt, int* __restrict__ bsum, int N) {
  __shared__ int s[256];
  const int t = threadIdx.x;
  const int base = blockIdx.x * SCAN_CHUNK;
  int v = 0;
  int i0 = base + t, i1 = base + 256 + t;
  if (i0 < N) v += cnt[i0];
  if (i1 < N) v += cnt[i1];
  s[t] = v;
  __syncthreads();
  for (int d = 128; d > 0; d >>= 1) {
    if (t < d) s[t] += s[t + d];
    __syncthreads();
  }
  if (t == 0) bsum[blockIdx.x] = s[0];
}

__global__ __launch_bounds__(256) void k_hist(
    const int* __restrict__ dst, int* __restrict__ cnt, int E) {
  const int e = blockIdx.x * blockDim.x + threadIdx.x;
  if (e < E) atomicAdd(&cnt[dst[e]], 1);
}

// ---------------------------------------------------------------------------
// Per-chunk exclusive scan writing pos; each block derives its own chunk
// prefix from bsum with a strided wave-0 reduction.
// ---------------------------------------------------------------------------
__global__ __launch_bounds__(256) void k_offsets(
    const int* __restrict__ cnt, const int* __restrict__ bsum,
    int* __restrict__ pos, int N) {
  __shared__ int s[256];
  __shared__ int sbase;
  const int t = threadIdx.x;
  if (t < 64) {
    int acc = 0;
    for (int j = t; j < (int)blockIdx.x; j += 64) acc += bsum[j];
    #pragma unroll
    for (int d = 1; d < 64; d <<= 1) acc += __shfl_xor(acc, d);
    if (t == 0) sbase = acc;
  }
  const int base = blockIdx.x * SCAN_CHUNK;
  const int i0 = base + 2 * t;
  const int i1 = i0 + 1;
  const int c0 = (i0 < N) ? cnt[i0] : 0;
  const int c1 = (i1 < N) ? cnt[i1] : 0;
  const int pair = c0 + c1;
  s[t] = pair;
  __syncthreads();
  #pragma unroll
  for (int d = 1; d < 256; d <<= 1) {
    int v = (t >= d) ? s[t - d] : 0;
    __syncthreads();
    s[t] += v;
    __syncthreads();
  }
  const int ex = s[t] - pair + sbase;  // exclusive prefix
  if (i0 < N) pos[i0] = ex;
  if (i1 < N) pos[i1] = ex + c0;
}

// 4 edges/thread, int4 loads.
__global__ __launch_bounds__(256) void k_scatter(
    const int* __restrict__ src, const int* __restrict__ dst,
    const int* __restrict__ etype, int* __restrict__ pos,
    int2* __restrict__ srcet, int E) {
  const int e0 = (blockIdx.x * blockDim.x + threadIdx.x) * 4;
  if (e0 + 3 < E) {
    const int4 s4 = *(const int4*)(src + e0);
    const int4 d4 = *(const int4*)(dst + e0);
    const int4 t4 = *(const int4*)(etype + e0);
    int p;
    p = atomicAdd(&pos[d4.x], 1); srcet[p] = make_int2(s4.x, t4.x);
    p = atomicAdd(&pos[d4.y], 1); srcet[p] = make_int2(s4.y, t4.y);
    p = atomicAdd(&pos[d4.z], 1); srcet[p] = make_int2(s4.z, t4.z);
    p = atomicAdd(&pos[d4.w], 1); srcet[p] = make_int2(s4.w, t4.w);
  } else {
    for (int e = e0; e < E; ++e) {
      const int p = atomicAdd(&pos[dst[e]], 1);
      srcet[p] = make_int2(src[e], etype[e]);
    }
  }
}

// ---------------------------------------------------------------------------
// bf16 aggregation (round-3 structure + grouped h loads): one wave per node;
// lane (b=lane>>2, opp=lane&3) owns outputs o=b*8+opp*2, o+1.
// Per 4-edge group: ONE 16B load fetches all 4 edges' h rows
// (lane = (edge=lane>>4, chunk=lane&15)), distributed per edge via 4 shfl.
// Per edge: 2 x 16B weight loads + 8 dot2. Epilogue prev/norm prefetched.
// out = relu(out + acc*norm)   (out holds loop_message).
// ---------------------------------------------------------------------------
__global__ __launch_bounds__(256) void agg_bf16(
    const unsigned short* __restrict__ h16, const float* __restrict__ norm,
    const unsigned short* __restrict__ w16, const int* __restrict__ pos,
    const int* __restrict__ cnt, const int2* __restrict__ srcet,
    float* __restrict__ out, int N) {
  const int node = (int)((blockIdx.x * blockDim.x + threadIdx.x) >> 6);
  const int lane = threadIdx.x & 63;
  if (node >= N) return;

  const int b = lane >> 2;
  const int opp = lane & 3;
  const int woff = b * 64 + opp * 16;  // ushort units
  const int o = b * 8 + opp * 2;

  const int num = cnt[node];
  const int end = pos[node];
  const int begin = end - num;

  // epilogue prefetch (out holds loop_message; gemm dispatch completed)
  float* outp = out + ((size_t)node << 7) + o;
  const float2 prev = *(const float2*)outp;
  const float nm = norm[node];

  float a0 = 0.f, a1 = 0.f;

  for (int base = 0; base < num; base += 64) {
    const int cn = min(64, num - base);
    const int2 my = srcet[begin + base + min(lane, cn - 1)];
    for (int i4 = 0; i4 < cn; i4 += 4) {
      // group h load: lane holds chunk (lane&15) of edge i4+(lane>>4)
      const int gl = min(i4 + (lane >> 4), cn - 1);
      const int sg = __shfl(my.x, gl);
      const uint4 xq =
          *(const uint4*)(h16 + ((size_t)sg << 7) + (lane & 15) * 8);
      const int nin = min(4, cn - i4);
      #pragma unroll 4
      for (int u = 0; u < nin; ++u) {
        const int r = __shfl(my.y, i4 + u);
        const int sl = u * 16 + b;
        uint4 xv;
        xv.x = __shfl(xq.x, sl);
        xv.y = __shfl(xq.y, sl);
        xv.z = __shfl(xq.z, sl);
        xv.w = __shfl(xq.w, sl);
        const unsigned short* wp = w16 + ((size_t)r << 10) + woff;
        const uint4 wa = *(const uint4*)(wp);
        const uint4 wb = *(const uint4*)(wp + 8);

        a0 = dot2bf(xv.x, wa.x, a0);
        a0 = dot2bf(xv.y, wa.y, a0);
        a0 = dot2bf(xv.z, wa.z, a0);
        a0 = dot2bf(xv.w, wa.w, a0);
        a1 = dot2bf(xv.x, wb.x, a1);
        a1 = dot2bf(xv.y, wb.y, a1);
        a1 = dot2bf(xv.z, wb.z, a1);
        a1 = dot2bf(xv.w, wb.w, a1);
      }
    }
  }

  float2 res;
  res.x = fmaxf(prev.x + a0 * nm, 0.f);
  res.y = fmaxf(prev.y + a1 * nm, 0.f);
  *(float2*)outp = res;
}

// ---------------------------------------------------------------------------
// f32 self-loop GEMM (fallback paths only).
// ---------------------------------------------------------------------------
__global__ __launch_bounds__(256) void selfloop_gemm(
    const float* __restrict__ h, const float* __restrict__ lw,
    float* __restrict__ out, int n) {
  __shared__ float slw[IN_FEAT * OUT_FEAT];  // 64 KB
  __shared__ float sh[32 * IN_FEAT];         // 16 KB

  {
    const float4* s4 = (const float4*)lw;
    float4* d4 = (float4*)slw;
    for (int i = threadIdx.x; i < IN_FEAT * OUT_FEAT / 4; i += 256) d4[i] = s4[i];
  }

  const int cg = threadIdx.x & 31;
  const int rg = threadIdx.x >> 5;

  for (int base = blockIdx.x * 32; base < n; base += gridDim.x * 32) {
    const int nrows = min(32, n - base);
    __syncthreads();
    {
      const float4* hs = (const float4*)(h + (size_t)base * IN_FEAT);
      float4* sd = (float4*)sh;
      const int cnt = nrows * (IN_FEAT / 4);
      for (int i = threadIdx.x; i < cnt; i += 256) sd[i] = hs[i];
    }
    __syncthreads();

    float4 acc[4];
    #pragma unroll
    for (int j = 0; j < 4; ++j) acc[j] = make_float4(0.f, 0.f, 0.f, 0.f);

    #pragma unroll 4
    for (int k = 0; k < IN_FEAT; ++k) {
      const float4 w = ((const float4*)slw)[k * 32 + cg];
      #pragma unroll
      for (int j = 0; j < 4; ++j) {
        const float hv = sh[(rg + 8 * j) * IN_FEAT + k];
        acc[j].x += hv * w.x;
        acc[j].y += hv * w.y;
        acc[j].z += hv * w.z;
        acc[j].w += hv * w.w;
      }
    }

    #pragma unroll
    for (int j = 0; j < 4; ++j) {
      const int r = rg + 8 * j;
      if (r < nrows) {
        ((float4*)(out + (size_t)(base + r) * OUT_FEAT))[cg] = acc[j];
      }
    }
  }
}

// ---------------------------------------------------------------------------
// f32 aggregation (middle fallback: ws fits sort but not bf16 buffers)
// ---------------------------------------------------------------------------
__global__ __launch_bounds__(256) void agg(
    const float* __restrict__ h, const float* __restrict__ norm,
    const float* __restrict__ weight, const int* __restrict__ pos,
    const int* __restrict__ cnt, const int2* __restrict__ srcet,
    float* __restrict__ out, int N) {
  const int node = (int)((blockIdx.x * blockDim.x + threadIdx.x) >> 6);
  const int lane = threadIdx.x & 63;
  if (node >= N) return;

  const int b = lane >> 2;
  const int op = (lane & 3) * 2;
  const int boff = b * 64 + op;

  const int num = cnt[node];
  const int end = pos[node];
  const int begin = end - num;

  float a0 = 0.f, a1 = 0.f;

  for (int base = 0; base < num; base += 64) {
    const int cn = min(64, num - base);
    const int2 my = srcet[begin + base + min(lane, cn - 1)];
    #pragma unroll 2
    for (int i = 0; i < cn; ++i) {
      const int s = __shfl(my.x, i);
      const int r = __shfl(my.y, i);
      const float* xp = h + ((size_t)s << 7) + b * 8;
      const float4 x0 = ((const float4*)xp)[0];
      const float4 x1 = ((const float4*)xp)[1];
      const float* wp = weight + ((size_t)r << 10) + boff;
      const float2 w0 = *(const float2*)(wp);
      const float2 w1 = *(const float2*)(wp + 8);
      const float2 w2 = *(const float2*)(wp + 16);
      const float2 w3 = *(const float2*)(wp + 24);
      const float2 w4 = *(const float2*)(wp + 32);
      const float2 w5 = *(const float2*)(wp + 40);
      const float2 w6 = *(const float2*)(wp + 48);
      const float2 w7 = *(const float2*)(wp + 56);
      a0 += x0.x * w0.x; a1 += x0.x * w0.y;
      a0 += x0.y * w1.x; a1 += x0.y * w1.y;
      a0 += x0.z * w2.x; a1 += x0.z * w2.y;
      a0 += x0.w * w3.x; a1 += x0.w * w3.y;
      a0 += x1.x * w4.x; a1 += x1.x * w4.y;
      a0 += x1.y * w5.x; a1 += x1.y * w5.y;
      a0 += x1.z * w6.x; a1 += x1.z * w6.y;
      a0 += x1.w * w7.x; a1 += x1.w * w7.y;
    }
  }

  const float nm = norm[node];
  const int o = b * 8 + op;
  float* outp = out + ((size_t)node << 7) + o;
  float2 prev = *(const float2*)outp;
  float2 res;
  res.x = fmaxf(prev.x + a0 * nm, 0.f);
  res.y = fmaxf(prev.y + a1 * nm, 0.f);
  *(float2*)outp = res;
}

// ---------------------------------------------------------------------------
// Last-resort fallback: per-edge atomics + separate relu.
// ---------------------------------------------------------------------------
__global__ __launch_bounds__(256) void edge_msg(
    const float* __restrict__ h, const float* __restrict__ norm,
    const float* __restrict__ weight, const int* __restrict__ src,
    const int* __restrict__ dst, const int* __restrict__ etype,
    float* out, int E) {
  const int wave = (int)((blockIdx.x * blockDim.x + threadIdx.x) >> 6);
  const int lane = threadIdx.x & 63;
  if (wave >= E) return;

  const int s = src[wave];
  const int d = dst[wave];
  const int r = etype[wave];
  const float nrm = norm[d];

  const int b = lane >> 2;
  const int op = (lane & 3) * 2;

  const float* xp = h + (size_t)s * IN_FEAT + b * 8;
  const float4 x0 = ((const float4*)xp)[0];
  const float4 x1 = ((const float4*)xp)[1];
  float x[8] = {x0.x, x0.y, x0.z, x0.w, x1.x, x1.y, x1.z, x1.w};

  const float* wp = weight + (size_t)r * 1024 + b * 64 + op;
  float a0 = 0.f, a1 = 0.f;
  #pragma unroll
  for (int i = 0; i < 8; ++i) {
    const float2 w = *(const float2*)(wp + i * 8);
    a0 += x[i] * w.x;
    a1 += x[i] * w.y;
  }

  const int o = b * 8 + op;
  float* outp = out + (size_t)d * OUT_FEAT + o;
  atomicAdd(outp, a0 * nrm);
  atomicAdd(outp + 1, a1 * nrm);
}

__global__ __launch_bounds__(256) void relu_k(float* __restrict__ out, int n4) {
  const int i = blockIdx.x * blockDim.x + threadIdx.x;
  if (i < n4) {
    float4 v = ((const float4*)out)[i];
    v.x = fmaxf(v.x, 0.f);
    v.y = fmaxf(v.y, 0.f);
    v.z = fmaxf(v.z, 0.f);
    v.w = fmaxf(v.w, 0.f);
    ((float4*)out)[i] = v;
  }
}

extern "C" void kernel_launch(void* const* d_in, const int* in_sizes, int n_in,
                              void* d_out, int out_size, void* d_ws, size_t ws_size,
                              hipStream_t stream) {
  const float* h    = (const float*)d_in[0];
  const float* norm = (const float*)d_in[1];
  const float* w    = (const float*)d_in[2];
  const float* lw   = (const float*)d_in[3];
  const int* src    = (const int*)d_in[4];
  const int* dst    = (const int*)d_in[5];
  const int* etype  = (const int*)d_in[6];
  float* out = (float*)d_out;

  const int N = in_sizes[1];            // norm has N elements
  const int E = in_sizes[4];            // src has E elements
  const int R = in_sizes[2] / 1024;     // weight rows
  const int nblk = (N + SCAN_CHUNK - 1) / SCAN_CHUNK;

  // ws layout: srcet[E] int2 | cnt[N] | pos[N] | bsum[max(nblk,128)] |
  //            h16[N*128] bf16 | w16[R*1024] bf16 | lwT[128*128] bf16
  const size_t nb_bsum = (size_t)((nblk < 128) ? 128 : nblk);
  const size_t off_cnt  = (size_t)E * 8;
  const size_t off_pos  = off_cnt + (size_t)N * 4;
  const size_t off_bsum = off_pos + (size_t)N * 4;
  size_t off_h16 = off_bsum + nb_bsum * 4;
  off_h16 = (off_h16 + 15) & ~(size_t)15;
  const size_t off_w16 = off_h16 + (size_t)N * IN_FEAT * 2;
  const size_t off_lwT = off_w16 + (size_t)R * 1024 * 2;
  const size_t need_full = off_lwT + (size_t)IN_FEAT * OUT_FEAT * 2;
  const size_t need_sort = off_bsum + nb_bsum * 4;

  if (ws_size >= need_full) {
    char* wsb = (char*)d_ws;
    int2* srcet = (int2*)wsb;
    int* cnt  = (int*)(wsb + off_cnt);
    int* pos  = (int*)(wsb + off_pos);
    int* bsum = (int*)(wsb + off_bsum);
    unsigned short* h16 = (unsigned short*)(wsb + off_h16);
    unsigned short* w16 = (unsigned short*)(wsb + off_w16);
    unsigned short* lwT = (unsigned short*)(wsb + off_lwT);

    hipMemsetAsync(cnt, 0, (size_t)N * 4, stream);

    // fused prologue: wpack (1 block/relation) + hpack + lwpack + hist (x4)
    const int htotal8 = N * IN_FEAT / 8;
    const int bw  = R;
    const int bh  = (htotal8 + 255) / 256;
    const int blw = (IN_FEAT * OUT_FEAT + 255) / 256;
    const int bhist = (E + 1023) / 1024;
    k_prep<<<bw + bh + blw + bhist, 256, 0, stream>>>(
        w, w16, h, (uint4*)h16, htotal8, lw, lwT, dst, cnt, E, bw, bh, blw);

    // fused: self-loop MFMA GEMM (out = loop_message) + chunk sums
    const int gemm_blocks = (N + 63) / 64;
    k_gemm_sum<<<gemm_blocks + nblk, 256, 0, stream>>>(
        h16, lwT, out, N, cnt, bsum, gemm_blocks);

    // offsets (inline bsum prefix) + scatter (4 edges/thread)
    k_offsets<<<nblk, 256, 0, stream>>>(cnt, bsum, pos, N);
    k_scatter<<<(E + 1023) / 1024, 256, 0, stream>>>(src, dst, etype, pos,
                                                     srcet, E);

    // one wave per node; fused norm + self-loop add + relu
    agg_bf16<<<(N + 3) / 4, 256, 0, stream>>>(h16, norm, w16, pos, cnt, srcet,
                                              out, N);
  } else if (ws_size >= need_sort) {
    char* wsb = (char*)d_ws;
    int2* srcet = (int2*)wsb;
    int* cnt  = (int*)(wsb + off_cnt);
    int* pos  = (int*)(wsb + off_pos);
    int* bsum = (int*)(wsb + off_bsum);

    selfloop_gemm<<<512, 256, 0, stream>>>(h, lw, out, N);
    hipMemsetAsync(cnt, 0, (size_t)N * 4, stream);
    k_hist<<<(E + 255) / 256, 256, 0, stream>>>(dst, cnt, E);
    k_chunksum<<<nblk, 256, 0, stream>>>(cnt, bsum, N);
    k_offsets<<<nblk, 256, 0, stream>>>(cnt, bsum, pos, N);
    k_scatter<<<(E + 1023) / 1024, 256, 0, stream>>>(src, dst, etype, pos,
                                                     srcet, E);
    agg<<<(N + 3) / 4, 256, 0, stream>>>(h, norm, w, pos, cnt, srcet, out, N);
  } else {
    selfloop_gemm<<<512, 256, 0, stream>>>(h, lw, out, N);
    edge_msg<<<(E + 3) / 4, 256, 0, stream>>>(h, norm, w, src, dst, etype, out, E);
    const int n4 = N * OUT_FEAT / 4;
    relu_k<<<(n4 + 255) / 256, 256, 0, stream>>>(out, n4);
  }
}